// Round 4
// baseline (878.155 us; speedup 1.0000x reference)
//
#include <hip/hip_runtime.h>
#include <hip/hip_bf16.h>

#define BB 16
#define LL 2048
#define DD 512
#define HH 1024
#define NL 4
#define MM (BB*LL)   // 32768

typedef __attribute__((ext_vector_type(8))) short bh8;
typedef __attribute__((ext_vector_type(4))) float f4;

typedef __attribute__((address_space(3))) unsigned int lds_u32;
typedef __attribute__((address_space(1))) const unsigned int glob_u32;

__device__ __forceinline__ void gld_lds16(const void* g, void* l) {
    __builtin_amdgcn_global_load_lds((glob_u32*)g, (lds_u32*)l, 16, 0, 0);
}

__device__ __forceinline__ unsigned short f2bf(float f) {
    unsigned int u = __float_as_uint(f);
    unsigned int r = (u + 0x7FFFu + ((u >> 16) & 1u)) >> 16;
    return (unsigned short)r;
}
__device__ __forceinline__ float bf2f(unsigned short u) {
    return __uint_as_float(((unsigned int)u) << 16);
}

// fast GELU (tanh form, abs err ~1e-4)
__device__ __forceinline__ float gelu_f(float v) {
    float y = 0.7978845608028654f * v * fmaf(0.044715f, v * v, 1.0f);
    float e = __expf(2.0f * y);
    float th = 1.0f - 2.0f * __builtin_amdgcn_rcpf(e + 1.0f);
    return 0.5f * v * (1.0f + th);
}

// ---------------- FREQS_CIS table [L, D]
__global__ __launch_bounds__(256) void freqs_kernel(float* __restrict__ fr) {
    int idx = blockIdx.x * 256 + threadIdx.x;
    int l = idx >> 8;
    int j = idx & 255;
    float f = exp2f(-(float)j * 0.051905126482615036f);  // log2(10000)/256
    float a = (float)l * f;
    fr[(size_t)l * DD + j]       = cosf(a);
    fr[(size_t)l * DD + 256 + j] = sinf(a);
}

// ---------------- weight transpose+convert: [NL][R][C] f32 -> [NL][C][R] bf16
__global__ __launch_bounds__(256) void wtrans_kernel(const float* __restrict__ w,
                                                     unsigned short* __restrict__ wt,
                                                     int R, int C) {
    __shared__ float ls[64][65];
    int layer = blockIdx.z;
    int tr = blockIdx.y;
    int tc = blockIdx.x;
    const float* src = w + (size_t)layer * R * C + (size_t)(tr * 64) * C + tc * 64;
    int t = threadIdx.x;
    #pragma unroll
    for (int s = 0; s < 4; s++) {
        int r = (t >> 4) + 16 * s, c = (t & 15) * 4;
        f4 v = *(const f4*)(src + (size_t)r * C + c);
        ls[r][c] = v.x; ls[r][c + 1] = v.y; ls[r][c + 2] = v.z; ls[r][c + 3] = v.w;
    }
    __syncthreads();
    unsigned short* dst = wt + (size_t)layer * R * C + (size_t)(tc * 64) * R + tr * 64;
    #pragma unroll
    for (int s = 0; s < 2; s++) {
        int idx = t + 256 * s;
        int c = idx >> 3;
        int r8 = (idx & 7) * 8;
        bh8 o;
        #pragma unroll
        for (int e = 0; e < 8; e++) o[e] = (short)f2bf(ls[r8 + e][c]);
        *(bh8*)(dst + (size_t)c * R + r8) = o;
    }
}

// ---------------- bias2[n] = pw2_b[n] + sum_k grn_b[k] * W2[k][n]  (absorbs GRN's +gb)
__global__ __launch_bounds__(256) void bias2_kernel(const float* __restrict__ pw2_b,
                                                    const float* __restrict__ grn_b,
                                                    const unsigned short* __restrict__ w2t,
                                                    float* __restrict__ bias2) {
    int layer = blockIdx.x;
    for (int n = threadIdx.x; n < DD; n += 256) {
        const unsigned short* wp = w2t + (size_t)layer * DD * HH + (size_t)n * HH;
        const float* gbp = grn_b + (size_t)layer * HH;
        float s = 0.f;
        for (int k8 = 0; k8 < HH; k8 += 8) {
            bh8 wv = *(const bh8*)(wp + k8);
            #pragma unroll
            for (int e = 0; e < 8; e++) s = fmaf(gbp[k8 + e], bf2f((unsigned short)wv[e]), s);
        }
        bias2[(size_t)layer * DD + n] = pw2_b[(size_t)layer * DD + n] + s;
    }
}

// ---------------- embedding + freqs + mask (float4)
__global__ __launch_bounds__(128) void embed_kernel(const int* __restrict__ text,
                                                    const float* __restrict__ table,
                                                    const float* __restrict__ fr,
                                                    float* __restrict__ x) {
    int bid = blockIdx.x;
    int d4 = threadIdx.x;
    int l = bid & (LL - 1);
    int tok = text[bid] + 1;
    f4 v = {0.f, 0.f, 0.f, 0.f};
    if (tok != 0) {
        f4 e = *(const f4*)(table + (size_t)tok * DD + d4 * 4);
        f4 f = *(const f4*)(fr + (size_t)l * DD + d4 * 4);
        v.x = e.x + f.x; v.y = e.y + f.y; v.z = e.z + f.z; v.w = e.w + f.w;
    }
    *(f4*)(x + (size_t)bid * DD + d4 * 4) = v;
}

// ---------------- depthwise conv7 + bias + LayerNorm -> bf16
#define CCH 16
__global__ __launch_bounds__(256) void conv_ln_kernel(const float* __restrict__ x,
                                                      const float* __restrict__ dw_w,
                                                      const float* __restrict__ dw_b,
                                                      const float* __restrict__ ln_g,
                                                      const float* __restrict__ ln_b,
                                                      unsigned short* __restrict__ xln) {
    const int t = threadIdx.x;
    const int lane = t & 63, wv = t >> 6;
    const int chunk = blockIdx.x * 4 + wv;
    const int row0 = chunk * CCH;
    const int l0 = row0 & (LL - 1);
    const int d0 = lane * 8;
    const float* xb = x + ((size_t)(row0 >> 11) * LL) * DD + d0;

    float w[7][8], cb[8], g[8], be[8];
    #pragma unroll
    for (int e = 0; e < 8; e++) {
        #pragma unroll
        for (int k = 0; k < 7; k++) w[k][e] = dw_w[(d0 + e) * 7 + k];
        cb[e] = dw_b[d0 + e];
        g[e]  = ln_g[d0 + e];
        be[e] = ln_b[d0 + e];
    }

    float ring[8][8];
    #pragma unroll
    for (int ii = 0; ii < 8; ii++) {
        int i = ii - 3;
        int s = i & 7;
        int l = l0 + i;
        bool ok = (unsigned)l < LL;
        f4 v0 = {0,0,0,0}, v1 = {0,0,0,0};
        if (ok) {
            const f4* p = (const f4*)(xb + (size_t)l * DD);
            v0 = p[0]; v1 = p[1];
        }
        ring[s][0]=v0.x; ring[s][1]=v0.y; ring[s][2]=v0.z; ring[s][3]=v0.w;
        ring[s][4]=v1.x; ring[s][5]=v1.y; ring[s][6]=v1.z; ring[s][7]=v1.w;
    }

    #pragma unroll
    for (int r = 0; r < CCH; r++) {
        float acc[8];
        #pragma unroll
        for (int e = 0; e < 8; e++) acc[e] = cb[e];
        #pragma unroll
        for (int k = 0; k < 7; k++) {
            int s = (r + k - 3) & 7;
            #pragma unroll
            for (int e = 0; e < 8; e++) acc[e] = fmaf(w[k][e], ring[s][e], acc[e]);
        }
        {
            int s = (r + 5) & 7;
            int l = l0 + r + 5;
            bool ok = (unsigned)l < LL;
            f4 v0 = {0,0,0,0}, v1 = {0,0,0,0};
            if (ok) {
                const f4* p = (const f4*)(xb + (size_t)l * DD);
                v0 = p[0]; v1 = p[1];
            }
            ring[s][0]=v0.x; ring[s][1]=v0.y; ring[s][2]=v0.z; ring[s][3]=v0.w;
            ring[s][4]=v1.x; ring[s][5]=v1.y; ring[s][6]=v1.z; ring[s][7]=v1.w;
        }
        float s1 = 0.f, s2 = 0.f;
        #pragma unroll
        for (int e = 0; e < 8; e++) { s1 += acc[e]; s2 = fmaf(acc[e], acc[e], s2); }
        #pragma unroll
        for (int off = 1; off <= 32; off <<= 1) {
            s1 += __shfl_xor(s1, off, 64);
            s2 += __shfl_xor(s2, off, 64);
        }
        float mu = s1 * (1.0f / DD);
        float var = s2 * (1.0f / DD) - mu * mu;
        float rstd = rsqrtf(var + 1e-6f);
        bh8 o;
        #pragma unroll
        for (int e = 0; e < 8; e++) o[e] = (short)f2bf((acc[e] - mu) * rstd * g[e] + be[e]);
        *(bh8*)(xln + (size_t)(row0 + r) * DD + d0) = o;
    }
}

// ---------------- bf16 MFMA GEMM, double-buffered 2-phase pipeline
// MODE 0 (GEMM1): h = bf16(gelu(C+bias)); also writes GRN row-block partials of sum(h^2)
// MODE 1 (GEMM2): A' = h * scale[b][k] staged in regs; x = mask ? 0 : (x + C + bias)
template<int KDIM, int NDIM, int MODE>
__global__ __launch_bounds__(256) void gemm_bf16_kernel(const unsigned short* __restrict__ A,
                                                        const unsigned short* __restrict__ Bt,
                                                        const float* __restrict__ bias,
                                                        unsigned short* __restrict__ hout,
                                                        float* __restrict__ xio,
                                                        const int* __restrict__ text,
                                                        float* __restrict__ aux) {
    __shared__ unsigned short lsA[2][128 * 32];
    __shared__ unsigned short lsB[2][128 * 32];
    const int t = threadIdx.x;
    constexpr int NX = NDIM / 128;
    constexpr int NWG = NX * (MM / 128);
    constexpr int NT = KDIM / 32;
    const int id = blockIdx.y * NX + blockIdx.x;
    const int sw = (id & 7) * (NWG / 8) + (id >> 3);     // XCD-chunked (NWG%8==0)
    const int m0 = (sw / NX) * 128;
    const int n0 = (sw % NX) * 128;

    const int lane = t & 63, wv = t >> 6;
    const int wr = wv >> 1, wc = wv & 1;
    const int rA = wr * 64 + (lane & 15);
    const int rB = wc * 64 + (lane & 15);
    const int kc = (lane >> 4) * 8;
    const int srow = t >> 2, scol = (t & 3) * 8;         // staging: lds byte = t*16

    const f4 vzero = {0.f, 0.f, 0.f, 0.f};
    f4 acc[4][4];
    #pragma unroll
    for (int i = 0; i < 4; i++)
        #pragma unroll
        for (int j = 0; j < 4; j++) acc[i][j] = vzero;

    const unsigned short* Ab = A + (size_t)m0 * KDIM;
    const unsigned short* Bb = Bt + (size_t)n0 * KDIM;
    const float* scale_p = (MODE == 1) ? (aux + (size_t)(m0 >> 11) * HH) : nullptr;

    // ---- prologue: stage tile 0 into buffer 0
    {
        const int ko = scol;
        gld_lds16(Bb + (size_t)srow * KDIM + ko,        &lsB[0][srow * 32 + scol]);
        gld_lds16(Bb + (size_t)(srow + 64) * KDIM + ko, &lsB[0][(srow + 64) * 32 + scol]);
        if constexpr (MODE == 0) {
            gld_lds16(Ab + (size_t)srow * KDIM + ko,        &lsA[0][srow * 32 + scol]);
            gld_lds16(Ab + (size_t)(srow + 64) * KDIM + ko, &lsA[0][(srow + 64) * 32 + scol]);
        } else {
            bh8 a0 = *(const bh8*)(Ab + (size_t)srow * KDIM + ko);
            bh8 a1 = *(const bh8*)(Ab + (size_t)(srow + 64) * KDIM + ko);
            f4 s0 = *(const f4*)(scale_p + ko);
            f4 s1 = *(const f4*)(scale_p + ko + 4);
            float sc[8] = {s0.x,s0.y,s0.z,s0.w,s1.x,s1.y,s1.z,s1.w};
            bh8 w0, w1;
            #pragma unroll
            for (int e = 0; e < 8; e++) {
                w0[e] = (short)f2bf(bf2f((unsigned short)a0[e]) * sc[e]);
                w1[e] = (short)f2bf(bf2f((unsigned short)a1[e]) * sc[e]);
            }
            *(bh8*)&lsA[0][srow * 32 + scol] = w0;
            *(bh8*)&lsA[0][(srow + 64) * 32 + scol] = w1;
        }
    }
    __syncthreads();

    int cur = 0;
    for (int kt = 0; kt < NT; kt++) {
        const bool do_stage = (kt + 1 < NT);
        bh8 a0, a1; float sc[8];
        if (do_stage) {
            const int ko = (kt + 1) * 32 + scol;
            gld_lds16(Bb + (size_t)srow * KDIM + ko,        &lsB[cur ^ 1][srow * 32 + scol]);
            gld_lds16(Bb + (size_t)(srow + 64) * KDIM + ko, &lsB[cur ^ 1][(srow + 64) * 32 + scol]);
            if constexpr (MODE == 0) {
                gld_lds16(Ab + (size_t)srow * KDIM + ko,        &lsA[cur ^ 1][srow * 32 + scol]);
                gld_lds16(Ab + (size_t)(srow + 64) * KDIM + ko, &lsA[cur ^ 1][(srow + 64) * 32 + scol]);
            } else {
                a0 = *(const bh8*)(Ab + (size_t)srow * KDIM + ko);
                a1 = *(const bh8*)(Ab + (size_t)(srow + 64) * KDIM + ko);
                f4 s0 = *(const f4*)(scale_p + ko);
                f4 s1 = *(const f4*)(scale_p + ko + 4);
                sc[0]=s0.x; sc[1]=s0.y; sc[2]=s0.z; sc[3]=s0.w;
                sc[4]=s1.x; sc[5]=s1.y; sc[6]=s1.z; sc[7]=s1.w;
            }
        }
        // compute on buffer `cur`
        bh8 af[4], bfv[4];
        #pragma unroll
        for (int i = 0; i < 4; i++) af[i]  = *(bh8*)&lsA[cur][(rA + i * 16) * 32 + kc];
        #pragma unroll
        for (int j = 0; j < 4; j++) bfv[j] = *(bh8*)&lsB[cur][(rB + j * 16) * 32 + kc];
        #pragma unroll
        for (int i = 0; i < 4; i++)
            #pragma unroll
            for (int j = 0; j < 4; j++)
                acc[i][j] = __builtin_amdgcn_mfma_f32_16x16x32_bf16(af[i], bfv[j], acc[i][j], 0, 0, 0);
        if constexpr (MODE == 1) {
            if (do_stage) {
                bh8 w0, w1;
                #pragma unroll
                for (int e = 0; e < 8; e++) {
                    w0[e] = (short)f2bf(bf2f((unsigned short)a0[e]) * sc[e]);
                    w1[e] = (short)f2bf(bf2f((unsigned short)a1[e]) * sc[e]);
                }
                *(bh8*)&lsA[cur ^ 1][srow * 32 + scol] = w0;
                *(bh8*)&lsA[cur ^ 1][(srow + 64) * 32 + scol] = w1;
            }
        }
        __syncthreads();
        cur ^= 1;
    }

    const int rowOff = (lane >> 4) * 4;
    const int colOff = lane & 15;
    if constexpr (MODE == 0) {
        float sj[4] = {0.f, 0.f, 0.f, 0.f};
        #pragma unroll
        for (int i = 0; i < 4; i++) {
            #pragma unroll
            for (int j = 0; j < 4; j++) {
                int n = n0 + wc * 64 + j * 16 + colOff;
                float bn = bias[n];
                #pragma unroll
                for (int r = 0; r < 4; r++) {
                    int m = m0 + wr * 64 + i * 16 + rowOff + r;
                    float v = gelu_f(acc[i][j][r] + bn);
                    hout[(size_t)m * NDIM + n] = f2bf(v);
                    sj[j] = fmaf(v, v, sj[j]);
                }
            }
        }
        // reduce sum over the wave's 64 rows: lanes sharing (lane&15) sum up
        #pragma unroll
        for (int j = 0; j < 4; j++) {
            sj[j] += __shfl_xor(sj[j], 16, 64);
            sj[j] += __shfl_xor(sj[j], 32, 64);
        }
        if (lane < 16) {
            int rb = (m0 >> 6) + wr;       // 0..511 row-block of 64 rows
            #pragma unroll
            for (int j = 0; j < 4; j++)
                aux[(size_t)rb * HH + n0 + wc * 64 + j * 16 + lane] = sj[j];
        }
    } else {
        #pragma unroll
        for (int i = 0; i < 4; i++) {
            #pragma unroll
            for (int j = 0; j < 4; j++) {
                int n = n0 + wc * 64 + j * 16 + colOff;
                float bn = bias[n];
                #pragma unroll
                for (int r = 0; r < 4; r++) {
                    int m = m0 + wr * 64 + i * 16 + rowOff + r;
                    size_t o = (size_t)m * NDIM + n;
                    float v = acc[i][j][r] + bn + xio[o];
                    if (text[m] == -1) v = 0.0f;
                    xio[o] = v;
                }
            }
        }
    }
}

// ---------------- GRN stats: scale[b][ch] = 1 + gg[ch] * Nx[b][ch]
__global__ __launch_bounds__(256) void grn_stats_kernel(const float* __restrict__ gxp,
                                                        const float* __restrict__ gg,
                                                        float* __restrict__ scale) {
    int b = blockIdx.x, t = threadIdx.x;
    float g[4];
    float s = 0.f;
    #pragma unroll
    for (int e = 0; e < 4; e++) {
        int ch = t + e * 256;
        float acc = 0.f;
        #pragma unroll
        for (int rb = 0; rb < 32; rb++) acc += gxp[(size_t)(b * 32 + rb) * HH + ch];
        g[e] = sqrtf(acc);
        s += g[e];
    }
    #pragma unroll
    for (int off = 32; off > 0; off >>= 1) s += __shfl_down(s, off);
    __shared__ float rs[4];
    if ((t & 63) == 0) rs[t >> 6] = s;
    __syncthreads();
    float tot = rs[0] + rs[1] + rs[2] + rs[3];
    float mean = tot * (1.0f / HH);
    float inv = 1.0f / (mean + 1e-6f);
    #pragma unroll
    for (int e = 0; e < 4; e++) {
        int ch = t + e * 256;
        scale[(size_t)b * HH + ch] = fmaf(gg[ch], g[e] * inv, 1.0f);
    }
}

// ---------------- upsample scan
__global__ __launch_bounds__(256) void upscan_kernel(const int* __restrict__ text,
                                                     const int* __restrict__ audio,
                                                     int* __restrict__ pos,
                                                     int* __restrict__ lens) {
    int b = blockIdx.x, t = threadIdx.x;
    __shared__ int sc[256];
    int voff = 0, aoff = 0;
    for (int c = 0; c < LL / 256; c++) {
        int l = c * 256 + t;
        int am = audio[(size_t)b * LL + l];
        int tv = text[(size_t)b * LL + l];
        int valid = (am != 0 && tv != -1) ? 1 : 0;
        sc[t] = valid;
        __syncthreads();
        for (int off = 1; off < 256; off <<= 1) {
            int add = (t >= off) ? sc[t - off] : 0;
            __syncthreads();
            sc[t] += add;
            __syncthreads();
        }
        int incl = sc[t];
        if (valid) pos[(size_t)b * LL + voff + incl - 1] = l;
        voff += sc[255];
        __syncthreads();
        sc[t] = (am != 0) ? 1 : 0;
        __syncthreads();
        for (int off = 128; off > 0; off >>= 1) {
            if (t < off) sc[t] += sc[t + off];
            __syncthreads();
        }
        aoff += sc[0];
        __syncthreads();
    }
    if (t == 0) { lens[b * 2] = aoff; lens[b * 2 + 1] = voff; }
    for (int i = voff + t; i < LL; i += 256) pos[(size_t)b * LL + i] = LL - 1;
}

// ---------------- upsample gather
__global__ __launch_bounds__(256) void upgather_kernel(const float* __restrict__ x,
                                                       const int* __restrict__ pos,
                                                       const int* __restrict__ lens,
                                                       float* __restrict__ out) {
    int bid = blockIdx.x;
    int b = bid >> 11;
    int p = bid & (LL - 1);
    int t = threadIdx.x;
    int alen = lens[b * 2], vlen = lens[b * 2 + 1];
    float v0 = 0.f, v1 = 0.f;
    if (p < alen && vlen > 0) {
        int vl = vlen < 1 ? 1 : vlen;
        int base = alen / vl, rem = alen % vl;
        int cut = (vl - rem) * base;
        int j;
        if (p < cut) j = p / (base < 1 ? 1 : base);
        else j = (vl - rem) + (p - cut) / (base + 1);
        j = j < 0 ? 0 : (j > LL - 1 ? LL - 1 : j);
        int s = pos[(size_t)b * LL + j];
        s = s < 0 ? 0 : (s > LL - 1 ? LL - 1 : s);
        const float* xr = x + ((size_t)b * LL + s) * DD;
        v0 = xr[t];
        v1 = xr[t + 256];
    }
    out[(size_t)bid * DD + t] = v0;
    out[(size_t)bid * DD + t + 256] = v1;
}

// ---------------- workspace layout (bytes)
#define OFF_FREQS  ((size_t)0)
#define OFF_X      (OFF_FREQS + (size_t)LL * DD * 4)          // 4 MB
#define OFF_XLN    (OFF_X + (size_t)MM * DD * 4)              // +64 MB
#define OFF_H      (OFF_XLN + (size_t)MM * DD * 2)            // +32 MB
#define OFF_W1T    (OFF_H + (size_t)MM * HH * 2)              // +64 MB
#define OFF_W2T    (OFF_W1T + (size_t)NL * HH * DD * 2)       // +4 MB
#define OFF_GXP    (OFF_W2T + (size_t)NL * DD * HH * 2)       // +4 MB
#define OFF_NX     (OFF_GXP + (size_t)512 * HH * 4)           // +2 MB (row-block partials)
#define OFF_B2     (OFF_NX + (size_t)BB * HH * 4)             // +64 KB (scale)
#define OFF_POS    (OFF_B2 + (size_t)NL * DD * 4)             // +8 KB
#define OFF_LENS   (OFF_POS + (size_t)BB * LL * 4)            // +128 KB

extern "C" void kernel_launch(void* const* d_in, const int* in_sizes, int n_in,
                              void* d_out, int out_size, void* d_ws, size_t ws_size,
                              hipStream_t stream) {
    const int*   text  = (const int*)d_in[0];
    const int*   audio = (const int*)d_in[1];
    const float* table = (const float*)d_in[3];
    const float* dw_w  = (const float*)d_in[4];
    const float* dw_b  = (const float*)d_in[5];
    const float* ln_g  = (const float*)d_in[6];
    const float* ln_b  = (const float*)d_in[7];
    const float* pw1_w = (const float*)d_in[8];
    const float* pw1_b = (const float*)d_in[9];
    const float* grn_g = (const float*)d_in[10];
    const float* grn_b = (const float*)d_in[11];
    const float* pw2_w = (const float*)d_in[12];
    const float* pw2_b = (const float*)d_in[13];
    float* out = (float*)d_out;

    char* ws = (char*)d_ws;
    float*          freqs = (float*)(ws + OFF_FREQS);
    float*          x     = (float*)(ws + OFF_X);
    unsigned short* xln   = (unsigned short*)(ws + OFF_XLN);
    unsigned short* h     = (unsigned short*)(ws + OFF_H);
    unsigned short* w1t   = (unsigned short*)(ws + OFF_W1T);
    unsigned short* w2t   = (unsigned short*)(ws + OFF_W2T);
    float*          gxp   = (float*)(ws + OFF_GXP);
    float*          nx    = (float*)(ws + OFF_NX);
    float*          bias2 = (float*)(ws + OFF_B2);
    int*            pos   = (int*)(ws + OFF_POS);
    int*            lens  = (int*)(ws + OFF_LENS);

    freqs_kernel<<<LL, 256, 0, stream>>>(freqs);
    wtrans_kernel<<<dim3(HH / 64, DD / 64, NL), 256, 0, stream>>>(pw1_w, w1t, DD, HH);
    wtrans_kernel<<<dim3(DD / 64, HH / 64, NL), 256, 0, stream>>>(pw2_w, w2t, HH, DD);
    bias2_kernel<<<NL, 256, 0, stream>>>(pw2_b, grn_b, w2t, bias2);
    embed_kernel<<<MM, 128, 0, stream>>>(text, table, freqs, x);

    for (int layer = 0; layer < NL; layer++) {
        conv_ln_kernel<<<MM / (4 * CCH), 256, 0, stream>>>(x,
            dw_w + (size_t)layer * DD * 7, dw_b + (size_t)layer * DD,
            ln_g + (size_t)layer * DD, ln_b + (size_t)layer * DD, xln);

        gemm_bf16_kernel<DD, HH, 0><<<dim3(HH / 128, MM / 128), 256, 0, stream>>>(
            xln, w1t + (size_t)layer * HH * DD, pw1_b + (size_t)layer * HH,
            h, nullptr, nullptr, gxp);

        grn_stats_kernel<<<BB, 256, 0, stream>>>(gxp, grn_g + (size_t)layer * HH, nx);

        gemm_bf16_kernel<HH, DD, 1><<<dim3(DD / 128, MM / 128), 256, 0, stream>>>(
            h, w2t + (size_t)layer * DD * HH, bias2 + (size_t)layer * DD,
            nullptr, x, text, nx);
    }

    upscan_kernel<<<BB, 256, 0, stream>>>(text, audio, pos, lens);
    upgather_kernel<<<MM, 256, 0, stream>>>(x, pos, lens, out);
}

// Round 5
// 725.691 us; speedup vs baseline: 1.2101x; 1.2101x over previous
//
#include <hip/hip_runtime.h>
#include <hip/hip_bf16.h>

#define BB 16
#define LL 2048
#define DD 512
#define HH 1024
#define NL 4
#define MM (BB*LL)   // 32768

typedef __attribute__((ext_vector_type(8))) short bh8;
typedef __attribute__((ext_vector_type(4))) float f4;

typedef __attribute__((address_space(3))) unsigned int lds_u32;
typedef __attribute__((address_space(1))) const unsigned int glob_u32;

__device__ __forceinline__ void gld_lds16(const void* g, void* l) {
    __builtin_amdgcn_global_load_lds((glob_u32*)g, (lds_u32*)l, 16, 0, 0);
}

__device__ __forceinline__ unsigned short f2bf(float f) {
    unsigned int u = __float_as_uint(f);
    unsigned int r = (u + 0x7FFFu + ((u >> 16) & 1u)) >> 16;
    return (unsigned short)r;
}
__device__ __forceinline__ float bf2f(unsigned short u) {
    return __uint_as_float(((unsigned int)u) << 16);
}

// fast GELU (tanh form, abs err ~1e-4)
__device__ __forceinline__ float gelu_f(float v) {
    float y = 0.7978845608028654f * v * fmaf(0.044715f, v * v, 1.0f);
    float e = __expf(2.0f * y);
    float th = 1.0f - 2.0f * __builtin_amdgcn_rcpf(e + 1.0f);
    return 0.5f * v * (1.0f + th);
}

// ---------------- FREQS_CIS table [L, D]
__global__ __launch_bounds__(256) void freqs_kernel(float* __restrict__ fr) {
    int idx = blockIdx.x * 256 + threadIdx.x;
    int l = idx >> 8;
    int j = idx & 255;
    float f = exp2f(-(float)j * 0.051905126482615036f);  // log2(10000)/256
    float a = (float)l * f;
    fr[(size_t)l * DD + j]       = cosf(a);
    fr[(size_t)l * DD + 256 + j] = sinf(a);
}

// ---------------- weight transpose+convert: [NL][R][C] f32 -> [NL][C][R] bf16
__global__ __launch_bounds__(256) void wtrans_kernel(const float* __restrict__ w,
                                                     unsigned short* __restrict__ wt,
                                                     int R, int C) {
    __shared__ float ls[64][65];
    int layer = blockIdx.z;
    int tr = blockIdx.y;
    int tc = blockIdx.x;
    const float* src = w + (size_t)layer * R * C + (size_t)(tr * 64) * C + tc * 64;
    int t = threadIdx.x;
    #pragma unroll
    for (int s = 0; s < 4; s++) {
        int r = (t >> 4) + 16 * s, c = (t & 15) * 4;
        f4 v = *(const f4*)(src + (size_t)r * C + c);
        ls[r][c] = v.x; ls[r][c + 1] = v.y; ls[r][c + 2] = v.z; ls[r][c + 3] = v.w;
    }
    __syncthreads();
    unsigned short* dst = wt + (size_t)layer * R * C + (size_t)(tc * 64) * R + tr * 64;
    #pragma unroll
    for (int s = 0; s < 2; s++) {
        int idx = t + 256 * s;
        int c = idx >> 3;
        int r8 = (idx & 7) * 8;
        bh8 o;
        #pragma unroll
        for (int e = 0; e < 8; e++) o[e] = (short)f2bf(ls[r8 + e][c]);
        *(bh8*)(dst + (size_t)c * R + r8) = o;
    }
}

// ---------------- bias2[n] = pw2_b[n] + sum_k grn_b[k] * W2[k][n]
__global__ __launch_bounds__(256) void bias2_kernel(const float* __restrict__ pw2_b,
                                                    const float* __restrict__ grn_b,
                                                    const unsigned short* __restrict__ w2t,
                                                    float* __restrict__ bias2) {
    int layer = blockIdx.x;
    for (int n = threadIdx.x; n < DD; n += 256) {
        const unsigned short* wp = w2t + (size_t)layer * DD * HH + (size_t)n * HH;
        const float* gbp = grn_b + (size_t)layer * HH;
        float s = 0.f;
        for (int k8 = 0; k8 < HH; k8 += 8) {
            bh8 wv = *(const bh8*)(wp + k8);
            #pragma unroll
            for (int e = 0; e < 8; e++) s = fmaf(gbp[k8 + e], bf2f((unsigned short)wv[e]), s);
        }
        bias2[(size_t)layer * DD + n] = pw2_b[(size_t)layer * DD + n] + s;
    }
}

// ---------------- embedding + freqs + mask (float4)
__global__ __launch_bounds__(128) void embed_kernel(const int* __restrict__ text,
                                                    const float* __restrict__ table,
                                                    const float* __restrict__ fr,
                                                    float* __restrict__ x) {
    int bid = blockIdx.x;
    int d4 = threadIdx.x;
    int l = bid & (LL - 1);
    int tok = text[bid] + 1;
    f4 v = {0.f, 0.f, 0.f, 0.f};
    if (tok != 0) {
        f4 e = *(const f4*)(table + (size_t)tok * DD + d4 * 4);
        f4 f = *(const f4*)(fr + (size_t)l * DD + d4 * 4);
        v.x = e.x + f.x; v.y = e.y + f.y; v.z = e.z + f.z; v.w = e.w + f.w;
    }
    *(f4*)(x + (size_t)bid * DD + d4 * 4) = v;
}

// ---------------- depthwise conv7 + bias + LayerNorm -> bf16
#define CCH 16
__global__ __launch_bounds__(256) void conv_ln_kernel(const float* __restrict__ x,
                                                      const float* __restrict__ dw_w,
                                                      const float* __restrict__ dw_b,
                                                      const float* __restrict__ ln_g,
                                                      const float* __restrict__ ln_b,
                                                      unsigned short* __restrict__ xln) {
    const int t = threadIdx.x;
    const int lane = t & 63, wv = t >> 6;
    const int chunk = blockIdx.x * 4 + wv;
    const int row0 = chunk * CCH;
    const int l0 = row0 & (LL - 1);
    const int d0 = lane * 8;
    const float* xb = x + ((size_t)(row0 >> 11) * LL) * DD + d0;

    float w[7][8], cb[8], g[8], be[8];
    #pragma unroll
    for (int e = 0; e < 8; e++) {
        #pragma unroll
        for (int k = 0; k < 7; k++) w[k][e] = dw_w[(d0 + e) * 7 + k];
        cb[e] = dw_b[d0 + e];
        g[e]  = ln_g[d0 + e];
        be[e] = ln_b[d0 + e];
    }

    float ring[8][8];
    #pragma unroll
    for (int ii = 0; ii < 8; ii++) {
        int i = ii - 3;
        int s = i & 7;
        int l = l0 + i;
        bool ok = (unsigned)l < LL;
        f4 v0 = {0,0,0,0}, v1 = {0,0,0,0};
        if (ok) {
            const f4* p = (const f4*)(xb + (size_t)l * DD);
            v0 = p[0]; v1 = p[1];
        }
        ring[s][0]=v0.x; ring[s][1]=v0.y; ring[s][2]=v0.z; ring[s][3]=v0.w;
        ring[s][4]=v1.x; ring[s][5]=v1.y; ring[s][6]=v1.z; ring[s][7]=v1.w;
    }

    #pragma unroll
    for (int r = 0; r < CCH; r++) {
        float acc[8];
        #pragma unroll
        for (int e = 0; e < 8; e++) acc[e] = cb[e];
        #pragma unroll
        for (int k = 0; k < 7; k++) {
            int s = (r + k - 3) & 7;
            #pragma unroll
            for (int e = 0; e < 8; e++) acc[e] = fmaf(w[k][e], ring[s][e], acc[e]);
        }
        {
            int s = (r + 5) & 7;
            int l = l0 + r + 5;
            bool ok = (unsigned)l < LL;
            f4 v0 = {0,0,0,0}, v1 = {0,0,0,0};
            if (ok) {
                const f4* p = (const f4*)(xb + (size_t)l * DD);
                v0 = p[0]; v1 = p[1];
            }
            ring[s][0]=v0.x; ring[s][1]=v0.y; ring[s][2]=v0.z; ring[s][3]=v0.w;
            ring[s][4]=v1.x; ring[s][5]=v1.y; ring[s][6]=v1.z; ring[s][7]=v1.w;
        }
        float s1 = 0.f, s2 = 0.f;
        #pragma unroll
        for (int e = 0; e < 8; e++) { s1 += acc[e]; s2 = fmaf(acc[e], acc[e], s2); }
        #pragma unroll
        for (int off = 1; off <= 32; off <<= 1) {
            s1 += __shfl_xor(s1, off, 64);
            s2 += __shfl_xor(s2, off, 64);
        }
        float mu = s1 * (1.0f / DD);
        float var = s2 * (1.0f / DD) - mu * mu;
        float rstd = rsqrtf(var + 1e-6f);
        bh8 o;
        #pragma unroll
        for (int e = 0; e < 8; e++) o[e] = (short)f2bf((acc[e] - mu) * rstd * g[e] + be[e]);
        *(bh8*)(xln + (size_t)(row0 + r) * DD + d0) = o;
    }
}

// ---------------- bf16 MFMA GEMM: single-buffer 2-barrier, BK=64, XOR-swizzled LDS
// (linear gld_lds dest + inverse-swizzled GLOBAL source + swizzled ds_read — rule #21)
// MODE 0 (GEMM1): h = bf16(gelu(C+bias)); writes 64-row-block partials of sum(h^2) to aux
// MODE 1 (GEMM2): B is per-batch pre-scaled W2 (batch = m0>>11); x = mask ? 0 : (x + C + bias)
template<int KDIM, int NDIM, int MODE>
__global__ __launch_bounds__(256) void gemm_bf16_kernel(const unsigned short* __restrict__ A,
                                                        const unsigned short* __restrict__ Bt,
                                                        const float* __restrict__ bias,
                                                        unsigned short* __restrict__ hout,
                                                        float* __restrict__ xio,
                                                        const int* __restrict__ text,
                                                        float* __restrict__ aux) {
    __shared__ unsigned short lsA[128 * 64];
    __shared__ unsigned short lsB[128 * 64];
    const int t = threadIdx.x;
    constexpr int NX = NDIM / 128;
    constexpr int NWG = NX * (MM / 128);
    constexpr int NT = KDIM / 64;
    const int id = blockIdx.y * NX + blockIdx.x;
    const int sw = (id & 7) * (NWG / 8) + (id >> 3);     // XCD-chunked (NWG%8==0)
    const int m0 = (sw / NX) * 128;
    const int n0 = (sw % NX) * 128;

    const int lane = t & 63, wv = t >> 6;
    const int wr = wv >> 1, wc = wv & 1;
    const int rA = wr * 64 + (lane & 15);
    const int rB = wc * 64 + (lane & 15);
    const int kcs = (lane >> 4) * 8;                 // logical k offset (shorts) in 32-chunk
    const int swz = (lane & 7) << 3;                 // read-side XOR (shorts)
    // staging: thread t covers row (s*32 + (t>>3)), LDS flat byte = s*4096 + t*16 (linear)
    const int srow = t >> 3;
    const int scolL = (((t & 7) ^ (srow & 7)) << 3); // inverse-swizzled global col (shorts)
    const int sdst = t * 8;                          // LDS dest (shorts), + s*2048

    const f4 vzero = {0.f, 0.f, 0.f, 0.f};
    f4 acc[4][4];
    #pragma unroll
    for (int i = 0; i < 4; i++)
        #pragma unroll
        for (int j = 0; j < 4; j++) acc[i][j] = vzero;

    const unsigned short* Ab = A + (size_t)m0 * KDIM + srow * KDIM + scolL;
    const unsigned short* Bb;
    if constexpr (MODE == 0) Bb = Bt + ((size_t)n0 + srow) * KDIM + scolL;
    else                     Bb = Bt + ((size_t)(m0 >> 11) * NDIM + n0 + srow) * KDIM + scolL;

    for (int kt = 0; kt < NT; kt++) {
        __syncthreads();
        const int ko = kt * 64;
        #pragma unroll
        for (int s = 0; s < 4; s++) {
            gld_lds16(Ab + (size_t)(s * 32) * KDIM + ko, &lsA[s * 2048 + sdst]);
            gld_lds16(Bb + (size_t)(s * 32) * KDIM + ko, &lsB[s * 2048 + sdst]);
        }
        __syncthreads();
        #pragma unroll
        for (int kk = 0; kk < 2; kk++) {
            const int kq = (kk * 32 + kcs) ^ swz;
            bh8 af[4], bfv[4];
            #pragma unroll
            for (int i = 0; i < 4; i++) af[i]  = *(bh8*)&lsA[(rA + i * 16) * 64 + kq];
            #pragma unroll
            for (int j = 0; j < 4; j++) bfv[j] = *(bh8*)&lsB[(rB + j * 16) * 64 + kq];
            #pragma unroll
            for (int i = 0; i < 4; i++)
                #pragma unroll
                for (int j = 0; j < 4; j++)
                    acc[i][j] = __builtin_amdgcn_mfma_f32_16x16x32_bf16(af[i], bfv[j], acc[i][j], 0, 0, 0);
        }
    }

    const int rowOff = (lane >> 4) * 4;
    const int colOff = lane & 15;
    if constexpr (MODE == 0) {
        float sj[4] = {0.f, 0.f, 0.f, 0.f};
        #pragma unroll
        for (int i = 0; i < 4; i++) {
            #pragma unroll
            for (int j = 0; j < 4; j++) {
                int n = n0 + wc * 64 + j * 16 + colOff;
                float bn = bias[n];
                #pragma unroll
                for (int r = 0; r < 4; r++) {
                    int m = m0 + wr * 64 + i * 16 + rowOff + r;
                    float v = gelu_f(acc[i][j][r] + bn);
                    hout[(size_t)m * NDIM + n] = f2bf(v);
                    sj[j] = fmaf(v, v, sj[j]);
                }
            }
        }
        #pragma unroll
        for (int j = 0; j < 4; j++) {
            sj[j] += __shfl_xor(sj[j], 16, 64);
            sj[j] += __shfl_xor(sj[j], 32, 64);
        }
        if (lane < 16) {
            int rb = (m0 >> 6) + wr;       // 0..511 row-block of 64 rows
            #pragma unroll
            for (int j = 0; j < 4; j++)
                aux[(size_t)rb * HH + n0 + wc * 64 + j * 16 + lane] = sj[j];
        }
    } else {
        #pragma unroll
        for (int i = 0; i < 4; i++) {
            #pragma unroll
            for (int j = 0; j < 4; j++) {
                int n = n0 + wc * 64 + j * 16 + colOff;
                float bn = bias[n];
                #pragma unroll
                for (int r = 0; r < 4; r++) {
                    int m = m0 + wr * 64 + i * 16 + rowOff + r;
                    size_t o = (size_t)m * NDIM + n;
                    float v = acc[i][j][r] + bn + xio[o];
                    if (text[m] == -1) v = 0.0f;
                    xio[o] = v;
                }
            }
        }
    }
}

// ---------------- GRN stats: scale[b][ch] = 1 + gg[ch] * Nx[b][ch]
__global__ __launch_bounds__(256) void grn_stats_kernel(const float* __restrict__ gxp,
                                                        const float* __restrict__ gg,
                                                        float* __restrict__ scale) {
    int b = blockIdx.x, t = threadIdx.x;
    float g[4];
    float s = 0.f;
    #pragma unroll
    for (int e = 0; e < 4; e++) {
        int ch = t + e * 256;
        float acc = 0.f;
        #pragma unroll
        for (int rb = 0; rb < 32; rb++) acc += gxp[(size_t)(b * 32 + rb) * HH + ch];
        g[e] = sqrtf(acc);
        s += g[e];
    }
    #pragma unroll
    for (int off = 32; off > 0; off >>= 1) s += __shfl_down(s, off);
    __shared__ float rs[4];
    if ((t & 63) == 0) rs[t >> 6] = s;
    __syncthreads();
    float tot = rs[0] + rs[1] + rs[2] + rs[3];
    float mean = tot * (1.0f / HH);
    float inv = 1.0f / (mean + 1e-6f);
    #pragma unroll
    for (int e = 0; e < 4; e++) {
        int ch = t + e * 256;
        scale[(size_t)b * HH + ch] = fmaf(gg[ch], g[e] * inv, 1.0f);
    }
}

// ---------------- per-batch scaled W2: w2s[b][n][k] = bf16(scale[b][k] * w2t[n][k])
__global__ __launch_bounds__(256) void w2scale_kernel(const unsigned short* __restrict__ w2t,
                                                      const float* __restrict__ scale,
                                                      unsigned short* __restrict__ w2s) {
    int b = blockIdx.y;
    size_t idx = ((size_t)blockIdx.x * 256 + threadIdx.x) * 8;   // over DD*HH
    int k = (int)(idx & (HH - 1));
    bh8 w = *(const bh8*)(w2t + idx);
    f4 s0 = *(const f4*)(scale + (size_t)b * HH + k);
    f4 s1 = *(const f4*)(scale + (size_t)b * HH + k + 4);
    float sv[8] = {s0.x,s0.y,s0.z,s0.w,s1.x,s1.y,s1.z,s1.w};
    bh8 o;
    #pragma unroll
    for (int e = 0; e < 8; e++) o[e] = (short)f2bf(bf2f((unsigned short)w[e]) * sv[e]);
    *(bh8*)(w2s + (size_t)b * DD * HH + idx) = o;
}

// ---------------- upsample scan
__global__ __launch_bounds__(256) void upscan_kernel(const int* __restrict__ text,
                                                     const int* __restrict__ audio,
                                                     int* __restrict__ pos,
                                                     int* __restrict__ lens) {
    int b = blockIdx.x, t = threadIdx.x;
    __shared__ int sc[256];
    int voff = 0, aoff = 0;
    for (int c = 0; c < LL / 256; c++) {
        int l = c * 256 + t;
        int am = audio[(size_t)b * LL + l];
        int tv = text[(size_t)b * LL + l];
        int valid = (am != 0 && tv != -1) ? 1 : 0;
        sc[t] = valid;
        __syncthreads();
        for (int off = 1; off < 256; off <<= 1) {
            int add = (t >= off) ? sc[t - off] : 0;
            __syncthreads();
            sc[t] += add;
            __syncthreads();
        }
        int incl = sc[t];
        if (valid) pos[(size_t)b * LL + voff + incl - 1] = l;
        voff += sc[255];
        __syncthreads();
        sc[t] = (am != 0) ? 1 : 0;
        __syncthreads();
        for (int off = 128; off > 0; off >>= 1) {
            if (t < off) sc[t] += sc[t + off];
            __syncthreads();
        }
        aoff += sc[0];
        __syncthreads();
    }
    if (t == 0) { lens[b * 2] = aoff; lens[b * 2 + 1] = voff; }
    for (int i = voff + t; i < LL; i += 256) pos[(size_t)b * LL + i] = LL - 1;
}

// ---------------- upsample gather
__global__ __launch_bounds__(256) void upgather_kernel(const float* __restrict__ x,
                                                       const int* __restrict__ pos,
                                                       const int* __restrict__ lens,
                                                       float* __restrict__ out) {
    int bid = blockIdx.x;
    int b = bid >> 11;
    int p = bid & (LL - 1);
    int t = threadIdx.x;
    int alen = lens[b * 2], vlen = lens[b * 2 + 1];
    float v0 = 0.f, v1 = 0.f;
    if (p < alen && vlen > 0) {
        int vl = vlen < 1 ? 1 : vlen;
        int base = alen / vl, rem = alen % vl;
        int cut = (vl - rem) * base;
        int j;
        if (p < cut) j = p / (base < 1 ? 1 : base);
        else j = (vl - rem) + (p - cut) / (base + 1);
        j = j < 0 ? 0 : (j > LL - 1 ? LL - 1 : j);
        int s = pos[(size_t)b * LL + j];
        s = s < 0 ? 0 : (s > LL - 1 ? LL - 1 : s);
        const float* xr = x + ((size_t)b * LL + s) * DD;
        v0 = xr[t];
        v1 = xr[t + 256];
    }
    out[(size_t)bid * DD + t] = v0;
    out[(size_t)bid * DD + t + 256] = v1;
}

// ---------------- workspace layout (bytes)
#define OFF_FREQS  ((size_t)0)
#define OFF_X      (OFF_FREQS + (size_t)LL * DD * 4)          // 4 MB
#define OFF_XLN    (OFF_X + (size_t)MM * DD * 4)              // +64 MB
#define OFF_H      (OFF_XLN + (size_t)MM * DD * 2)            // +32 MB
#define OFF_W1T    (OFF_H + (size_t)MM * HH * 2)              // +64 MB
#define OFF_W2T    (OFF_W1T + (size_t)NL * HH * DD * 2)       // +4 MB
#define OFF_GXP    (OFF_W2T + (size_t)NL * DD * HH * 2)       // +4 MB
#define OFF_NX     (OFF_GXP + (size_t)512 * HH * 4)           // +2 MB
#define OFF_B2     (OFF_NX + (size_t)BB * HH * 4)             // +64 KB
#define OFF_POS    (OFF_B2 + (size_t)NL * DD * 4)             // +8 KB
#define OFF_LENS   (OFF_POS + (size_t)BB * LL * 4)            // +128 KB
// w2s (16 MB) overlays xln's 32 MB region: xln is dead from end of GEMM1(layer)
// until conv_ln(layer+1); w2s is live only grn_stats->GEMM2 of the same layer.
#define OFF_W2S    OFF_XLN

extern "C" void kernel_launch(void* const* d_in, const int* in_sizes, int n_in,
                              void* d_out, int out_size, void* d_ws, size_t ws_size,
                              hipStream_t stream) {
    const int*   text  = (const int*)d_in[0];
    const int*   audio = (const int*)d_in[1];
    const float* table = (const float*)d_in[3];
    const float* dw_w  = (const float*)d_in[4];
    const float* dw_b  = (const float*)d_in[5];
    const float* ln_g  = (const float*)d_in[6];
    const float* ln_b  = (const float*)d_in[7];
    const float* pw1_w = (const float*)d_in[8];
    const float* pw1_b = (const float*)d_in[9];
    const float* grn_g = (const float*)d_in[10];
    const float* grn_b = (const float*)d_in[11];
    const float* pw2_w = (const float*)d_in[12];
    const float* pw2_b = (const float*)d_in[13];
    float* out = (float*)d_out;

    char* ws = (char*)d_ws;
    float*          freqs = (float*)(ws + OFF_FREQS);
    float*          x     = (float*)(ws + OFF_X);
    unsigned short* xln   = (unsigned short*)(ws + OFF_XLN);
    unsigned short* h     = (unsigned short*)(ws + OFF_H);
    unsigned short* w1t   = (unsigned short*)(ws + OFF_W1T);
    unsigned short* w2t   = (unsigned short*)(ws + OFF_W2T);
    unsigned short* w2s   = (unsigned short*)(ws + OFF_W2S);
    float*          gxp   = (float*)(ws + OFF_GXP);
    float*          nx    = (float*)(ws + OFF_NX);
    float*          bias2 = (float*)(ws + OFF_B2);
    int*            pos   = (int*)(ws + OFF_POS);
    int*            lens  = (int*)(ws + OFF_LENS);

    freqs_kernel<<<LL, 256, 0, stream>>>(freqs);
    wtrans_kernel<<<dim3(HH / 64, DD / 64, NL), 256, 0, stream>>>(pw1_w, w1t, DD, HH);
    wtrans_kernel<<<dim3(DD / 64, HH / 64, NL), 256, 0, stream>>>(pw2_w, w2t, HH, DD);
    bias2_kernel<<<NL, 256, 0, stream>>>(pw2_b, grn_b, w2t, bias2);
    embed_kernel<<<MM, 128, 0, stream>>>(text, table, freqs, x);

    for (int layer = 0; layer < NL; layer++) {
        conv_ln_kernel<<<MM / (4 * CCH), 256, 0, stream>>>(x,
            dw_w + (size_t)layer * DD * 7, dw_b + (size_t)layer * DD,
            ln_g + (size_t)layer * DD, ln_b + (size_t)layer * DD, xln);

        gemm_bf16_kernel<DD, HH, 0><<<dim3(HH / 128, MM / 128), 256, 0, stream>>>(
            xln, w1t + (size_t)layer * HH * DD, pw1_b + (size_t)layer * HH,
            h, nullptr, nullptr, gxp);

        grn_stats_kernel<<<BB, 256, 0, stream>>>(gxp, grn_g + (size_t)layer * HH, nx);

        w2scale_kernel<<<dim3(DD * HH / (256 * 8), BB), 256, 0, stream>>>(
            w2t + (size_t)layer * DD * HH, nx, w2s);

        gemm_bf16_kernel<HH, DD, 1><<<dim3(DD / 128, MM / 128), 256, 0, stream>>>(
            h, w2s, bias2 + (size_t)layer * DD,
            nullptr, x, text, gxp);
    }

    upscan_kernel<<<BB, 256, 0, stream>>>(text, audio, pos, lens);
    upgather_kernel<<<MM, 256, 0, stream>>>(x, pos, lens, out);
}

// Round 6
// 691.339 us; speedup vs baseline: 1.2702x; 1.0497x over previous
//
#include <hip/hip_runtime.h>
#include <hip/hip_bf16.h>

#define BB 16
#define LL 2048
#define DD 512
#define HH 1024
#define NL 4
#define MM (BB*LL)   // 32768

typedef __attribute__((ext_vector_type(8))) short bh8;
typedef __attribute__((ext_vector_type(4))) float f4;

typedef __attribute__((address_space(3))) unsigned int lds_u32;
typedef __attribute__((address_space(1))) const unsigned int glob_u32;

__device__ __forceinline__ void gld_lds16(const void* g, void* l) {
    __builtin_amdgcn_global_load_lds((glob_u32*)g, (lds_u32*)l, 16, 0, 0);
}

__device__ __forceinline__ unsigned short f2bf(float f) {
    unsigned int u = __float_as_uint(f);
    unsigned int r = (u + 0x7FFFu + ((u >> 16) & 1u)) >> 16;
    return (unsigned short)r;
}
__device__ __forceinline__ float bf2f(unsigned short u) {
    return __uint_as_float(((unsigned int)u) << 16);
}

// fast GELU (tanh form, abs err ~1e-4)
__device__ __forceinline__ float gelu_f(float v) {
    float y = 0.7978845608028654f * v * fmaf(0.044715f, v * v, 1.0f);
    float e = __expf(2.0f * y);
    float th = 1.0f - 2.0f * __builtin_amdgcn_rcpf(e + 1.0f);
    return 0.5f * v * (1.0f + th);
}

// ---------------- FREQS_CIS table [L, D]
__global__ __launch_bounds__(256) void freqs_kernel(float* __restrict__ fr) {
    int idx = blockIdx.x * 256 + threadIdx.x;
    int l = idx >> 8;
    int j = idx & 255;
    float f = exp2f(-(float)j * 0.051905126482615036f);  // log2(10000)/256
    float a = (float)l * f;
    fr[(size_t)l * DD + j]       = cosf(a);
    fr[(size_t)l * DD + 256 + j] = sinf(a);
}

// ---------------- weight transpose+convert: [NL][R][C] f32 -> [NL][C][R] bf16
__global__ __launch_bounds__(256) void wtrans_kernel(const float* __restrict__ w,
                                                     unsigned short* __restrict__ wt,
                                                     int R, int C) {
    __shared__ float ls[64][65];
    int layer = blockIdx.z;
    int tr = blockIdx.y;
    int tc = blockIdx.x;
    const float* src = w + (size_t)layer * R * C + (size_t)(tr * 64) * C + tc * 64;
    int t = threadIdx.x;
    #pragma unroll
    for (int s = 0; s < 4; s++) {
        int r = (t >> 4) + 16 * s, c = (t & 15) * 4;
        f4 v = *(const f4*)(src + (size_t)r * C + c);
        ls[r][c] = v.x; ls[r][c + 1] = v.y; ls[r][c + 2] = v.z; ls[r][c + 3] = v.w;
    }
    __syncthreads();
    unsigned short* dst = wt + (size_t)layer * R * C + (size_t)(tc * 64) * R + tr * 64;
    #pragma unroll
    for (int s = 0; s < 2; s++) {
        int idx = t + 256 * s;
        int c = idx >> 3;
        int r8 = (idx & 7) * 8;
        bh8 o;
        #pragma unroll
        for (int e = 0; e < 8; e++) o[e] = (short)f2bf(ls[r8 + e][c]);
        *(bh8*)(dst + (size_t)c * R + r8) = o;
    }
}

// ---------------- bias2[n] = pw2_b[n] + sum_k grn_b[k] * W2[k][n]
__global__ __launch_bounds__(256) void bias2_kernel(const float* __restrict__ pw2_b,
                                                    const float* __restrict__ grn_b,
                                                    const unsigned short* __restrict__ w2t,
                                                    float* __restrict__ bias2) {
    int layer = blockIdx.x;
    for (int n = threadIdx.x; n < DD; n += 256) {
        const unsigned short* wp = w2t + (size_t)layer * DD * HH + (size_t)n * HH;
        const float* gbp = grn_b + (size_t)layer * HH;
        float s = 0.f;
        for (int k8 = 0; k8 < HH; k8 += 8) {
            bh8 wv = *(const bh8*)(wp + k8);
            #pragma unroll
            for (int e = 0; e < 8; e++) s = fmaf(gbp[k8 + e], bf2f((unsigned short)wv[e]), s);
        }
        bias2[(size_t)layer * DD + n] = pw2_b[(size_t)layer * DD + n] + s;
    }
}

// ---------------- embedding + freqs + mask (float4)
__global__ __launch_bounds__(128) void embed_kernel(const int* __restrict__ text,
                                                    const float* __restrict__ table,
                                                    const float* __restrict__ fr,
                                                    float* __restrict__ x) {
    int bid = blockIdx.x;
    int d4 = threadIdx.x;
    int l = bid & (LL - 1);
    int tok = text[bid] + 1;
    f4 v = {0.f, 0.f, 0.f, 0.f};
    if (tok != 0) {
        f4 e = *(const f4*)(table + (size_t)tok * DD + d4 * 4);
        f4 f = *(const f4*)(fr + (size_t)l * DD + d4 * 4);
        v.x = e.x + f.x; v.y = e.y + f.y; v.z = e.z + f.z; v.w = e.w + f.w;
    }
    *(f4*)(x + (size_t)bid * DD + d4 * 4) = v;
}

// ---------------- depthwise conv7 + bias + LayerNorm -> bf16
#define CCH 16
__global__ __launch_bounds__(256) void conv_ln_kernel(const float* __restrict__ x,
                                                      const float* __restrict__ dw_w,
                                                      const float* __restrict__ dw_b,
                                                      const float* __restrict__ ln_g,
                                                      const float* __restrict__ ln_b,
                                                      unsigned short* __restrict__ xln) {
    const int t = threadIdx.x;
    const int lane = t & 63, wv = t >> 6;
    const int chunk = blockIdx.x * 4 + wv;
    const int row0 = chunk * CCH;
    const int l0 = row0 & (LL - 1);
    const int d0 = lane * 8;
    const float* xb = x + ((size_t)(row0 >> 11) * LL) * DD + d0;

    float w[7][8], cb[8], g[8], be[8];
    #pragma unroll
    for (int e = 0; e < 8; e++) {
        #pragma unroll
        for (int k = 0; k < 7; k++) w[k][e] = dw_w[(d0 + e) * 7 + k];
        cb[e] = dw_b[d0 + e];
        g[e]  = ln_g[d0 + e];
        be[e] = ln_b[d0 + e];
    }

    float ring[8][8];
    #pragma unroll
    for (int ii = 0; ii < 8; ii++) {
        int i = ii - 3;
        int s = i & 7;
        int l = l0 + i;
        bool ok = (unsigned)l < LL;
        f4 v0 = {0,0,0,0}, v1 = {0,0,0,0};
        if (ok) {
            const f4* p = (const f4*)(xb + (size_t)l * DD);
            v0 = p[0]; v1 = p[1];
        }
        ring[s][0]=v0.x; ring[s][1]=v0.y; ring[s][2]=v0.z; ring[s][3]=v0.w;
        ring[s][4]=v1.x; ring[s][5]=v1.y; ring[s][6]=v1.z; ring[s][7]=v1.w;
    }

    #pragma unroll
    for (int r = 0; r < CCH; r++) {
        float acc[8];
        #pragma unroll
        for (int e = 0; e < 8; e++) acc[e] = cb[e];
        #pragma unroll
        for (int k = 0; k < 7; k++) {
            int s = (r + k - 3) & 7;
            #pragma unroll
            for (int e = 0; e < 8; e++) acc[e] = fmaf(w[k][e], ring[s][e], acc[e]);
        }
        {
            int s = (r + 5) & 7;
            int l = l0 + r + 5;
            bool ok = (unsigned)l < LL;
            f4 v0 = {0,0,0,0}, v1 = {0,0,0,0};
            if (ok) {
                const f4* p = (const f4*)(xb + (size_t)l * DD);
                v0 = p[0]; v1 = p[1];
            }
            ring[s][0]=v0.x; ring[s][1]=v0.y; ring[s][2]=v0.z; ring[s][3]=v0.w;
            ring[s][4]=v1.x; ring[s][5]=v1.y; ring[s][6]=v1.z; ring[s][7]=v1.w;
        }
        float s1 = 0.f, s2 = 0.f;
        #pragma unroll
        for (int e = 0; e < 8; e++) { s1 += acc[e]; s2 = fmaf(acc[e], acc[e], s2); }
        #pragma unroll
        for (int off = 1; off <= 32; off <<= 1) {
            s1 += __shfl_xor(s1, off, 64);
            s2 += __shfl_xor(s2, off, 64);
        }
        float mu = s1 * (1.0f / DD);
        float var = s2 * (1.0f / DD) - mu * mu;
        float rstd = rsqrtf(var + 1e-6f);
        bh8 o;
        #pragma unroll
        for (int e = 0; e < 8; e++) o[e] = (short)f2bf((acc[e] - mu) * rstd * g[e] + be[e]);
        *(bh8*)(xln + (size_t)(row0 + r) * DD + d0) = o;
    }
}

// ---------------- bf16 MFMA GEMM: T3-minimum 2-phase pipeline (stage-early, counted drain,
// ONE raw s_barrier per K-tile), BK=64, XOR-swizzled LDS (linear gld_lds dest +
// inverse-swizzled global source + swizzled ds_read), XCD-chunked block swizzle, T5 setprio.
// MODE 0 (GEMM1): h = bf16(gelu(C+bias)); writes 64-row-block partials of sum(h^2) to aux
// MODE 1 (GEMM2): B is per-batch pre-scaled W2 (batch = m0>>11); x = mask ? 0 : (x + C + bias)
template<int KDIM, int NDIM, int MODE>
__global__ __launch_bounds__(256) void gemm_bf16_kernel(const unsigned short* __restrict__ A,
                                                        const unsigned short* __restrict__ Bt,
                                                        const float* __restrict__ bias,
                                                        unsigned short* __restrict__ hout,
                                                        float* __restrict__ xio,
                                                        const int* __restrict__ text,
                                                        float* __restrict__ aux) {
    __shared__ unsigned short lsA0[128 * 64];
    __shared__ unsigned short lsB0[128 * 64];
    __shared__ unsigned short lsA1[128 * 64];
    __shared__ unsigned short lsB1[128 * 64];
    const int t = threadIdx.x;
    constexpr int NX = NDIM / 128;
    constexpr int NWG = NX * (MM / 128);
    constexpr int NT = KDIM / 64;
    const int id = blockIdx.y * NX + blockIdx.x;
    const int sw = (id & 7) * (NWG / 8) + (id >> 3);     // XCD-chunked (NWG%8==0)
    const int m0 = (sw / NX) * 128;
    const int n0 = (sw % NX) * 128;

    const int lane = t & 63, wv = t >> 6;
    const int wr = wv >> 1, wc = wv & 1;
    const int rA = wr * 64 + (lane & 15);
    const int rB = wc * 64 + (lane & 15);
    const int kcs = (lane >> 4) * 8;                 // logical k offset (shorts) in 32-chunk
    const int swz = (lane & 7) << 3;                 // read-side XOR (shorts)
    const int srow = t >> 3;
    const int scolL = (((t & 7) ^ (srow & 7)) << 3); // inverse-swizzled global col (shorts)
    const int sdst = t * 8;                          // LDS dest (shorts), + s*2048

    const f4 vzero = {0.f, 0.f, 0.f, 0.f};
    f4 acc[4][4];
    #pragma unroll
    for (int i = 0; i < 4; i++)
        #pragma unroll
        for (int j = 0; j < 4; j++) acc[i][j] = vzero;

    const unsigned short* Ab = A + (size_t)m0 * KDIM + srow * KDIM + scolL;
    const unsigned short* Bb;
    if constexpr (MODE == 0) Bb = Bt + ((size_t)n0 + srow) * KDIM + scolL;
    else                     Bb = Bt + ((size_t)(m0 >> 11) * NDIM + n0 + srow) * KDIM + scolL;

#define G_STAGE(dA, dB, ko)                                                        \
    _Pragma("unroll")                                                              \
    for (int s = 0; s < 4; s++) {                                                  \
        gld_lds16(Ab + (size_t)(s * 32) * KDIM + (ko), &(dA)[s * 2048 + sdst]);    \
        gld_lds16(Bb + (size_t)(s * 32) * KDIM + (ko), &(dB)[s * 2048 + sdst]);    \
    }

#define G_COMPUTE(sA, sB)                                                          \
    __builtin_amdgcn_s_setprio(1);                                                 \
    _Pragma("unroll")                                                              \
    for (int kk = 0; kk < 2; kk++) {                                               \
        const int kq = (kk * 32 + kcs) ^ swz;                                      \
        bh8 af[4], bfv[4];                                                         \
        _Pragma("unroll")                                                          \
        for (int i = 0; i < 4; i++) af[i]  = *(bh8*)&(sA)[(rA + i * 16) * 64 + kq];\
        _Pragma("unroll")                                                          \
        for (int j = 0; j < 4; j++) bfv[j] = *(bh8*)&(sB)[(rB + j * 16) * 64 + kq];\
        _Pragma("unroll")                                                          \
        for (int i = 0; i < 4; i++)                                                \
            _Pragma("unroll")                                                      \
            for (int j = 0; j < 4; j++)                                            \
                acc[i][j] = __builtin_amdgcn_mfma_f32_16x16x32_bf16(af[i], bfv[j], acc[i][j], 0, 0, 0); \
    }                                                                              \
    __builtin_amdgcn_s_setprio(0);

#define G_SYNC                                                                     \
    asm volatile("s_waitcnt vmcnt(0)" ::: "memory");                               \
    __builtin_amdgcn_s_barrier();                                                  \
    __builtin_amdgcn_sched_barrier(0);

    // prologue: stage tile 0 into buf0
    G_STAGE(lsA0, lsB0, 0)
    G_SYNC

    for (int kt = 0; kt < NT; kt += 2) {
        // tile kt in buf0; stage kt+1 into buf1 (kt+1 < NT always: NT even)
        G_STAGE(lsA1, lsB1, (kt + 1) * 64)
        G_COMPUTE(lsA0, lsB0)
        G_SYNC
        const bool more = (kt + 2 < NT);
        if (more) { G_STAGE(lsA0, lsB0, (kt + 2) * 64) }
        G_COMPUTE(lsA1, lsB1)
        if (more) { G_SYNC }
    }

#undef G_STAGE
#undef G_COMPUTE
#undef G_SYNC

    const int rowOff = (lane >> 4) * 4;
    const int colOff = lane & 15;
    if constexpr (MODE == 0) {
        float sj[4] = {0.f, 0.f, 0.f, 0.f};
        #pragma unroll
        for (int i = 0; i < 4; i++) {
            #pragma unroll
            for (int j = 0; j < 4; j++) {
                int n = n0 + wc * 64 + j * 16 + colOff;
                float bn = bias[n];
                #pragma unroll
                for (int r = 0; r < 4; r++) {
                    int m = m0 + wr * 64 + i * 16 + rowOff + r;
                    float v = gelu_f(acc[i][j][r] + bn);
                    hout[(size_t)m * NDIM + n] = f2bf(v);
                    sj[j] = fmaf(v, v, sj[j]);
                }
            }
        }
        #pragma unroll
        for (int j = 0; j < 4; j++) {
            sj[j] += __shfl_xor(sj[j], 16, 64);
            sj[j] += __shfl_xor(sj[j], 32, 64);
        }
        if (lane < 16) {
            int rb = (m0 >> 6) + wr;       // 0..511 row-block of 64 rows
            #pragma unroll
            for (int j = 0; j < 4; j++)
                aux[(size_t)rb * HH + n0 + wc * 64 + j * 16 + lane] = sj[j];
        }
    } else {
        #pragma unroll
        for (int i = 0; i < 4; i++) {
            #pragma unroll
            for (int j = 0; j < 4; j++) {
                int n = n0 + wc * 64 + j * 16 + colOff;
                float bn = bias[n];
                #pragma unroll
                for (int r = 0; r < 4; r++) {
                    int m = m0 + wr * 64 + i * 16 + rowOff + r;
                    size_t o = (size_t)m * NDIM + n;
                    float v = acc[i][j][r] + bn + xio[o];
                    if (text[m] == -1) v = 0.0f;
                    xio[o] = v;
                }
            }
        }
    }
}

// ---------------- GRN stats: scale[b][ch] = 1 + gg[ch] * Nx[b][ch]
__global__ __launch_bounds__(256) void grn_stats_kernel(const float* __restrict__ gxp,
                                                        const float* __restrict__ gg,
                                                        float* __restrict__ scale) {
    int b = blockIdx.x, t = threadIdx.x;
    float g[4];
    float s = 0.f;
    #pragma unroll
    for (int e = 0; e < 4; e++) {
        int ch = t + e * 256;
        float acc = 0.f;
        #pragma unroll
        for (int rb = 0; rb < 32; rb++) acc += gxp[(size_t)(b * 32 + rb) * HH + ch];
        g[e] = sqrtf(acc);
        s += g[e];
    }
    #pragma unroll
    for (int off = 32; off > 0; off >>= 1) s += __shfl_down(s, off);
    __shared__ float rs[4];
    if ((t & 63) == 0) rs[t >> 6] = s;
    __syncthreads();
    float tot = rs[0] + rs[1] + rs[2] + rs[3];
    float mean = tot * (1.0f / HH);
    float inv = 1.0f / (mean + 1e-6f);
    #pragma unroll
    for (int e = 0; e < 4; e++) {
        int ch = t + e * 256;
        scale[(size_t)b * HH + ch] = fmaf(gg[ch], g[e] * inv, 1.0f);
    }
}

// ---------------- per-batch scaled W2: w2s[b][n][k] = bf16(scale[b][k] * w2t[n][k])
__global__ __launch_bounds__(256) void w2scale_kernel(const unsigned short* __restrict__ w2t,
                                                      const float* __restrict__ scale,
                                                      unsigned short* __restrict__ w2s) {
    int b = blockIdx.y;
    size_t idx = ((size_t)blockIdx.x * 256 + threadIdx.x) * 8;   // over DD*HH
    int k = (int)(idx & (HH - 1));
    bh8 w = *(const bh8*)(w2t + idx);
    f4 s0 = *(const f4*)(scale + (size_t)b * HH + k);
    f4 s1 = *(const f4*)(scale + (size_t)b * HH + k + 4);
    float sv[8] = {s0.x,s0.y,s0.z,s0.w,s1.x,s1.y,s1.z,s1.w};
    bh8 o;
    #pragma unroll
    for (int e = 0; e < 8; e++) o[e] = (short)f2bf(bf2f((unsigned short)w[e]) * sv[e]);
    *(bh8*)(w2s + (size_t)b * DD * HH + idx) = o;
}

// ---------------- upsample scan
__global__ __launch_bounds__(256) void upscan_kernel(const int* __restrict__ text,
                                                     const int* __restrict__ audio,
                                                     int* __restrict__ pos,
                                                     int* __restrict__ lens) {
    int b = blockIdx.x, t = threadIdx.x;
    __shared__ int sc[256];
    int voff = 0, aoff = 0;
    for (int c = 0; c < LL / 256; c++) {
        int l = c * 256 + t;
        int am = audio[(size_t)b * LL + l];
        int tv = text[(size_t)b * LL + l];
        int valid = (am != 0 && tv != -1) ? 1 : 0;
        sc[t] = valid;
        __syncthreads();
        for (int off = 1; off < 256; off <<= 1) {
            int add = (t >= off) ? sc[t - off] : 0;
            __syncthreads();
            sc[t] += add;
            __syncthreads();
        }
        int incl = sc[t];
        if (valid) pos[(size_t)b * LL + voff + incl - 1] = l;
        voff += sc[255];
        __syncthreads();
        sc[t] = (am != 0) ? 1 : 0;
        __syncthreads();
        for (int off = 128; off > 0; off >>= 1) {
            if (t < off) sc[t] += sc[t + off];
            __syncthreads();
        }
        aoff += sc[0];
        __syncthreads();
    }
    if (t == 0) { lens[b * 2] = aoff; lens[b * 2 + 1] = voff; }
    for (int i = voff + t; i < LL; i += 256) pos[(size_t)b * LL + i] = LL - 1;
}

// ---------------- upsample gather
__global__ __launch_bounds__(256) void upgather_kernel(const float* __restrict__ x,
                                                       const int* __restrict__ pos,
                                                       const int* __restrict__ lens,
                                                       float* __restrict__ out) {
    int bid = blockIdx.x;
    int b = bid >> 11;
    int p = bid & (LL - 1);
    int t = threadIdx.x;
    int alen = lens[b * 2], vlen = lens[b * 2 + 1];
    float v0 = 0.f, v1 = 0.f;
    if (p < alen && vlen > 0) {
        int vl = vlen < 1 ? 1 : vlen;
        int base = alen / vl, rem = alen % vl;
        int cut = (vl - rem) * base;
        int j;
        if (p < cut) j = p / (base < 1 ? 1 : base);
        else j = (vl - rem) + (p - cut) / (base + 1);
        j = j < 0 ? 0 : (j > LL - 1 ? LL - 1 : j);
        int s = pos[(size_t)b * LL + j];
        s = s < 0 ? 0 : (s > LL - 1 ? LL - 1 : s);
        const float* xr = x + ((size_t)b * LL + s) * DD;
        v0 = xr[t];
        v1 = xr[t + 256];
    }
    out[(size_t)bid * DD + t] = v0;
    out[(size_t)bid * DD + t + 256] = v1;
}

// ---------------- workspace layout (bytes)
#define OFF_FREQS  ((size_t)0)
#define OFF_X      (OFF_FREQS + (size_t)LL * DD * 4)          // 4 MB
#define OFF_XLN    (OFF_X + (size_t)MM * DD * 4)              // +64 MB
#define OFF_H      (OFF_XLN + (size_t)MM * DD * 2)            // +32 MB
#define OFF_W1T    (OFF_H + (size_t)MM * HH * 2)              // +64 MB
#define OFF_W2T    (OFF_W1T + (size_t)NL * HH * DD * 2)       // +4 MB
#define OFF_GXP    (OFF_W2T + (size_t)NL * DD * HH * 2)       // +4 MB
#define OFF_NX     (OFF_GXP + (size_t)512 * HH * 4)           // +2 MB
#define OFF_B2     (OFF_NX + (size_t)BB * HH * 4)             // +64 KB
#define OFF_POS    (OFF_B2 + (size_t)NL * DD * 4)             // +8 KB
#define OFF_LENS   (OFF_POS + (size_t)BB * LL * 4)            // +128 KB
// w2s (16 MB) overlays xln's region (xln dead between GEMM1(layer) and conv_ln(layer+1))
#define OFF_W2S    OFF_XLN

extern "C" void kernel_launch(void* const* d_in, const int* in_sizes, int n_in,
                              void* d_out, int out_size, void* d_ws, size_t ws_size,
                              hipStream_t stream) {
    const int*   text  = (const int*)d_in[0];
    const int*   audio = (const int*)d_in[1];
    const float* table = (const float*)d_in[3];
    const float* dw_w  = (const float*)d_in[4];
    const float* dw_b  = (const float*)d_in[5];
    const float* ln_g  = (const float*)d_in[6];
    const float* ln_b  = (const float*)d_in[7];
    const float* pw1_w = (const float*)d_in[8];
    const float* pw1_b = (const float*)d_in[9];
    const float* grn_g = (const float*)d_in[10];
    const float* grn_b = (const float*)d_in[11];
    const float* pw2_w = (const float*)d_in[12];
    const float* pw2_b = (const float*)d_in[13];
    float* out = (float*)d_out;

    char* ws = (char*)d_ws;
    float*          freqs = (float*)(ws + OFF_FREQS);
    float*          x     = (float*)(ws + OFF_X);
    unsigned short* xln   = (unsigned short*)(ws + OFF_XLN);
    unsigned short* h     = (unsigned short*)(ws + OFF_H);
    unsigned short* w1t   = (unsigned short*)(ws + OFF_W1T);
    unsigned short* w2t   = (unsigned short*)(ws + OFF_W2T);
    unsigned short* w2s   = (unsigned short*)(ws + OFF_W2S);
    float*          gxp   = (float*)(ws + OFF_GXP);
    float*          nx    = (float*)(ws + OFF_NX);
    float*          bias2 = (float*)(ws + OFF_B2);
    int*            pos   = (int*)(ws + OFF_POS);
    int*            lens  = (int*)(ws + OFF_LENS);

    freqs_kernel<<<LL, 256, 0, stream>>>(freqs);
    wtrans_kernel<<<dim3(HH / 64, DD / 64, NL), 256, 0, stream>>>(pw1_w, w1t, DD, HH);
    wtrans_kernel<<<dim3(DD / 64, HH / 64, NL), 256, 0, stream>>>(pw2_w, w2t, HH, DD);
    bias2_kernel<<<NL, 256, 0, stream>>>(pw2_b, grn_b, w2t, bias2);
    embed_kernel<<<MM, 128, 0, stream>>>(text, table, freqs, x);

    for (int layer = 0; layer < NL; layer++) {
        conv_ln_kernel<<<MM / (4 * CCH), 256, 0, stream>>>(x,
            dw_w + (size_t)layer * DD * 7, dw_b + (size_t)layer * DD,
            ln_g + (size_t)layer * DD, ln_b + (size_t)layer * DD, xln);

        gemm_bf16_kernel<DD, HH, 0><<<dim3(HH / 128, MM / 128), 256, 0, stream>>>(
            xln, w1t + (size_t)layer * HH * DD, pw1_b + (size_t)layer * HH,
            h, nullptr, nullptr, gxp);

        grn_stats_kernel<<<BB, 256, 0, stream>>>(gxp, grn_g + (size_t)layer * HH, nx);

        w2scale_kernel<<<dim3(DD * HH / (256 * 8), BB), 256, 0, stream>>>(
            w2t + (size_t)layer * DD * HH, nx, w2s);

        gemm_bf16_kernel<HH, DD, 1><<<dim3(DD / 128, MM / 128), 256, 0, stream>>>(
            h, w2s, bias2 + (size_t)layer * DD,
            nullptr, x, text, gxp);
    }

    upscan_kernel<<<BB, 256, 0, stream>>>(text, audio, pos, lens);
    upgather_kernel<<<MM, 256, 0, stream>>>(x, pos, lens, out);
}